// Round 2
// baseline (185.209 us; speedup 1.0000x reference)
//
#include <hip/hip_runtime.h>
#include <hip/hip_bf16.h>

#define POOL 7
#define NCH 256
#define OUT_PER_BOX (NCH * POOL * POOL)   // 12544

__global__ __launch_bounds__(256) void roi_align_kernel(
    const float* __restrict__ boxes,
    const float* __restrict__ p2,
    const float* __restrict__ p3,
    const float* __restrict__ p4,
    const float* __restrict__ p5,
    float* __restrict__ out)
{
    const int n   = blockIdx.x;
    const int tid = threadIdx.x;

    __shared__ int   s_y0[POOL], s_y1[POOL], s_x0[POOL], s_x1[POOL];
    __shared__ float s_wy[POOL], s_wx[POOL], s_vy[POOL], s_vx[POOL];

    // Every thread computes the box params + level (broadcast loads, uniform).
    const float by1 = boxes[n * 4 + 0];
    const float bx1 = boxes[n * 4 + 1];
    const float by2 = boxes[n * 4 + 2];
    const float bx2 = boxes[n * 4 + 3];
    const float h = by2 - by1;
    const float w = bx2 - bx1;

    // roi_level = clip(round(4 + log2(sqrt(h*w) / (224/1024))), 2, 5)
    const float lvlf = 4.0f + log2f(sqrtf(h * w) / 0.21875f);
    int lvl = (int)rintf(lvlf);          // round-half-to-even, matches np/jnp.round
    lvl = lvl < 2 ? 2 : (lvl > 5 ? 5 : lvl);

    const float* fm;
    int H;
    switch (lvl) {
        case 2:  fm = p2; H = 256; break;
        case 3:  fm = p3; H = 128; break;
        case 4:  fm = p4; H = 64;  break;
        default: fm = p5; H = 32;  break;
    }
    const float Hm1 = (float)(H - 1);

    if (tid < POOL) {
        const float t = (float)tid * (1.0f / 6.0f);

        // y samples
        const float yy  = (by1 + h * t) * Hm1;
        const float y0f = floorf(yy);
        int y0 = (int)y0f;
        y0 = min(H - 1, max(0, y0));
        s_y0[tid] = y0;
        s_y1[tid] = min(H - 1, y0 + 1);
        s_wy[tid] = yy - y0f;                       // weight from UNCLIPPED floor
        s_vy[tid] = (yy >= 0.0f && yy <= Hm1) ? 1.0f : 0.0f;

        // x samples
        const float xx  = (bx1 + w * t) * Hm1;
        const float x0f = floorf(xx);
        int x0 = (int)x0f;
        x0 = min(H - 1, max(0, x0));
        s_x0[tid] = x0;
        s_x1[tid] = min(H - 1, x0 + 1);
        s_wx[tid] = xx - x0f;
        s_vx[tid] = (xx >= 0.0f && xx <= Hm1) ? 1.0f : 0.0f;
    }
    __syncthreads();

    const size_t out_base = (size_t)n * OUT_PER_BOX;
    const int HW = H * H;

    for (int idx = tid; idx < OUT_PER_BOX; idx += 256) {
        const int c  = idx / 49;
        const int r  = idx - c * 49;
        const int py = r / 7;
        const int px = r - py * 7;

        const float* fmc = fm + (size_t)c * HW;

        const int   y0  = s_y0[py], y1i = s_y1[py];
        const int   x0  = s_x0[px], x1i = s_x1[px];
        const float wy  = s_wy[py], wx  = s_wx[px];

        const float v00 = fmc[y0  * H + x0 ];
        const float v01 = fmc[y0  * H + x1i];
        const float v10 = fmc[y1i * H + x0 ];
        const float v11 = fmc[y1i * H + x1i];

        const float omwy = 1.0f - wy, omwx = 1.0f - wx;
        float val = v00 * omwy * omwx + v01 * omwy * wx +
                    v10 * wy   * omwx + v11 * wy   * wx;
        val *= s_vy[py] * s_vx[px];

        out[out_base + idx] = val;
    }
}

extern "C" void kernel_launch(void* const* d_in, const int* in_sizes, int n_in,
                              void* d_out, int out_size, void* d_ws, size_t ws_size,
                              hipStream_t stream) {
    const float* boxes = (const float*)d_in[0];
    const float* p2    = (const float*)d_in[1];
    const float* p3    = (const float*)d_in[2];
    const float* p4    = (const float*)d_in[3];
    const float* p5    = (const float*)d_in[4];
    float* out         = (float*)d_out;

    const int nbox = in_sizes[0] / 4;   // 1000
    roi_align_kernel<<<nbox, 256, 0, stream>>>(boxes, p2, p3, p4, p5, out);
}

// Round 3
// 167.282 us; speedup vs baseline: 1.1072x; 1.1072x over previous
//
#include <hip/hip_runtime.h>
#include <hip/hip_bf16.h>

#define POOL 7
#define NCH 256
#define OUT_PER_BOX (NCH * POOL * POOL)   // 12544 = 7 * 1792
#define PARTS 7
#define PART_SZ (OUT_PER_BOX / PARTS)     // 1792 = 7 * 256

__global__ __launch_bounds__(256) void roi_align_kernel(
    const float* __restrict__ boxes,
    const float* __restrict__ p2,
    const float* __restrict__ p3,
    const float* __restrict__ p4,
    const float* __restrict__ p5,
    float* __restrict__ out,
    int nbox)
{
    // part-major decode: same-box parts are blockIdx strides of nbox (1000),
    // 1000 % 8 == 0 -> all 7 parts of a box land on the same XCD (round-robin
    // heuristic) so the box's gather lines live in ONE XCD's L2, not 7 copies.
    const int n    = blockIdx.x % nbox;
    const int part = blockIdx.x / nbox;
    const int tid  = threadIdx.x;

    __shared__ int   s_y0[POOL], s_y1[POOL], s_x0[POOL], s_x1[POOL];
    __shared__ float s_wy[POOL], s_wx[POOL], s_vy[POOL], s_vx[POOL];

    const float by1 = boxes[n * 4 + 0];
    const float bx1 = boxes[n * 4 + 1];
    const float by2 = boxes[n * 4 + 2];
    const float bx2 = boxes[n * 4 + 3];
    const float h = by2 - by1;
    const float w = bx2 - bx1;

    // roi_level = clip(round(4 + log2(sqrt(h*w) / (224/1024))), 2, 5)
    const float lvlf = 4.0f + log2f(sqrtf(h * w) / 0.21875f);
    int lvl = (int)rintf(lvlf);          // round-half-to-even, matches jnp.round
    lvl = lvl < 2 ? 2 : (lvl > 5 ? 5 : lvl);

    const float* fm;
    int H;
    switch (lvl) {
        case 2:  fm = p2; H = 256; break;
        case 3:  fm = p3; H = 128; break;
        case 4:  fm = p4; H = 64;  break;
        default: fm = p5; H = 32;  break;
    }
    const float Hm1 = (float)(H - 1);

    if (tid < POOL) {
        const float t = (float)tid * (1.0f / 6.0f);

        const float yy  = (by1 + h * t) * Hm1;
        const float y0f = floorf(yy);
        int y0 = (int)y0f;
        y0 = min(H - 1, max(0, y0));
        s_y0[tid] = y0;
        s_y1[tid] = min(H - 1, y0 + 1);
        s_wy[tid] = yy - y0f;                       // weight from UNCLIPPED floor
        s_vy[tid] = (yy >= 0.0f && yy <= Hm1) ? 1.0f : 0.0f;

        const float xx  = (bx1 + w * t) * Hm1;
        const float x0f = floorf(xx);
        int x0 = (int)x0f;
        x0 = min(H - 1, max(0, x0));
        s_x0[tid] = x0;
        s_x1[tid] = min(H - 1, x0 + 1);
        s_wx[tid] = xx - x0f;
        s_vx[tid] = (xx >= 0.0f && xx <= Hm1) ? 1.0f : 0.0f;
    }
    __syncthreads();

    const size_t out_base = (size_t)n * OUT_PER_BOX + (size_t)part * PART_SZ;
    const int idx0 = part * PART_SZ + tid;
    const int HW = H * H;

    // Exactly 7 iterations, fully unrolled -> up to 28 gathers in flight.
    #pragma unroll
    for (int i = 0; i < PART_SZ / 256; ++i) {
        const int idx = idx0 + i * 256;

        const int c  = idx / 49;
        const int r  = idx - c * 49;
        const int py = r / 7;
        const int px = r - py * 7;

        const float* fmc = fm + (size_t)c * HW;

        const int   y0  = s_y0[py], y1i = s_y1[py];
        const int   x0  = s_x0[px], x1i = s_x1[px];
        const float wy  = s_wy[py], wx  = s_wx[px];

        const float v00 = fmc[y0  * H + x0 ];
        const float v01 = fmc[y0  * H + x1i];
        const float v10 = fmc[y1i * H + x0 ];
        const float v11 = fmc[y1i * H + x1i];

        const float omwy = 1.0f - wy, omwx = 1.0f - wx;
        float val = v00 * omwy * omwx + v01 * omwy * wx +
                    v10 * wy   * omwx + v11 * wy   * wx;
        val *= s_vy[py] * s_vx[px];

        out[out_base + (size_t)(i * 256 + tid)] = val;
    }
}

extern "C" void kernel_launch(void* const* d_in, const int* in_sizes, int n_in,
                              void* d_out, int out_size, void* d_ws, size_t ws_size,
                              hipStream_t stream) {
    const float* boxes = (const float*)d_in[0];
    const float* p2    = (const float*)d_in[1];
    const float* p3    = (const float*)d_in[2];
    const float* p4    = (const float*)d_in[3];
    const float* p5    = (const float*)d_in[4];
    float* out         = (float*)d_out;

    const int nbox = in_sizes[0] / 4;   // 1000
    roi_align_kernel<<<nbox * PARTS, 256, 0, stream>>>(boxes, p2, p3, p4, p5, out, nbox);
}

// Round 5
// 154.535 us; speedup vs baseline: 1.1985x; 1.0825x over previous
//
#include <hip/hip_runtime.h>

#define POOL 7
#define NCH 256
#define OUT_PER_BOX (NCH * POOL * POOL)   // 12544 = 7 * 1792
#define PARTS 7
#define PART_SZ (OUT_PER_BOX / PARTS)     // 1792 = 7 * 256
#define ITERS (PART_SZ / 256)             // 7

__global__ __launch_bounds__(256) void roi_align_kernel(
    const float* __restrict__ boxes,
    const float* __restrict__ p2,
    const float* __restrict__ p3,
    const float* __restrict__ p4,
    const float* __restrict__ p5,
    float* __restrict__ out,
    int nbox)
{
    // part-major decode: same-box parts are blockIdx strides of nbox (1000),
    // 1000 % 8 == 0 -> all 7 parts of a box land on the same XCD.
    const int n    = blockIdx.x % nbox;
    const int part = blockIdx.x / nbox;
    const int tid  = threadIdx.x;

    __shared__ int   s_y0[POOL], s_y1[POOL], s_xb[POOL], s_xcl[POOL];
    __shared__ float s_wy[POOL], s_wx[POOL], s_vy[POOL], s_vx[POOL];

    const float by1 = boxes[n * 4 + 0];
    const float bx1 = boxes[n * 4 + 1];
    const float by2 = boxes[n * 4 + 2];
    const float bx2 = boxes[n * 4 + 3];
    const float h = by2 - by1;
    const float w = bx2 - bx1;

    // roi_level = clip(round(4 + log2(sqrt(h*w) / (224/1024))), 2, 5)
    const float lvlf = 4.0f + log2f(sqrtf(h * w) / 0.21875f);
    int lvl = (int)rintf(lvlf);          // round-half-to-even, matches jnp.round
    lvl = lvl < 2 ? 2 : (lvl > 5 ? 5 : lvl);

    const float* fm;
    int H;
    switch (lvl) {
        case 2:  fm = p2; H = 256; break;
        case 3:  fm = p3; H = 128; break;
        case 4:  fm = p4; H = 64;  break;
        default: fm = p5; H = 32;  break;
    }
    const float Hm1 = (float)(H - 1);

    if (tid < POOL) {
        const float t = (float)tid * (1.0f / 6.0f);

        const float yy  = (by1 + h * t) * Hm1;
        const float y0f = floorf(yy);
        int y0 = (int)y0f;
        y0 = min(H - 1, max(0, y0));
        s_y0[tid] = y0;
        s_y1[tid] = min(H - 1, y0 + 1);
        s_wy[tid] = yy - y0f;                       // weight from UNCLIPPED floor
        s_vy[tid] = (yy >= 0.0f && yy <= Hm1) ? 1.0f : 0.0f;

        const float xx  = (bx1 + w * t) * Hm1;
        const float x0f = floorf(xx);
        int x0 = (int)x0f;
        x0 = min(H - 1, max(0, x0));
        // paired-load base: float2 at xb covers {xb, xb+1}.
        //   x0 <= H-2 : v00 = pair.x, v01 = pair.y   (x1 = x0+1)
        //   x0 == H-1 : v00 = v01 = pair.y           (x1 = x0, clamped)
        s_xb[tid]  = min(x0, H - 2);
        s_xcl[tid] = (x0 == H - 1) ? 1 : 0;
        s_wx[tid]  = xx - x0f;
        s_vx[tid]  = (xx >= 0.0f && xx <= Hm1) ? 1.0f : 0.0f;
    }
    __syncthreads();

    const size_t out_base = (size_t)n * OUT_PER_BOX + (size_t)part * PART_SZ;
    const int idx0 = part * PART_SZ + tid;
    const int HW = H * H;

    // Phase 1: issue all 14 dwordx2 gathers, keep results in registers.
    float2 q0[ITERS], q1[ITERS];
    #pragma unroll
    for (int i = 0; i < ITERS; ++i) {
        const int idx = idx0 + i * 256;
        const int c  = idx / 49;
        const int r  = idx - c * 49;
        const int py = r / 7;
        const int px = r - py * 7;

        const float* fmc = fm + (size_t)c * HW;
        const int xb = s_xb[px];
        q0[i] = *(const float2*)(fmc + s_y0[py] * H + xb);
        q1[i] = *(const float2*)(fmc + s_y1[py] * H + xb);
    }

    // Phase 2: lerp + store (coalesced).
    #pragma unroll
    for (int i = 0; i < ITERS; ++i) {
        const int idx = idx0 + i * 256;
        const int c  = idx / 49;
        const int r  = idx - c * 49;
        const int py = r / 7;
        const int px = r - py * 7;

        const float wy = s_wy[py], wx = s_wx[px];
        const int   cl = s_xcl[px];

        const float v00 = cl ? q0[i].y : q0[i].x;
        const float v01 = q0[i].y;
        const float v10 = cl ? q1[i].y : q1[i].x;
        const float v11 = q1[i].y;

        const float r0 = v00 + wx * (v01 - v00);
        const float r1 = v10 + wx * (v11 - v10);
        float val = (r0 + wy * (r1 - r0)) * s_vy[py] * s_vx[px];

        out[out_base + (size_t)(i * 256 + tid)] = val;
    }
}

extern "C" void kernel_launch(void* const* d_in, const int* in_sizes, int n_in,
                              void* d_out, int out_size, void* d_ws, size_t ws_size,
                              hipStream_t stream) {
    const float* boxes = (const float*)d_in[0];
    const float* p2    = (const float*)d_in[1];
    const float* p3    = (const float*)d_in[2];
    const float* p4    = (const float*)d_in[3];
    const float* p5    = (const float*)d_in[4];
    float* out         = (float*)d_out;

    const int nbox = in_sizes[0] / 4;   // 1000
    roi_align_kernel<<<nbox * PARTS, 256, 0, stream>>>(boxes, p2, p3, p4, p5, out, nbox);
}